// Round 9
// baseline (12883.618 us; speedup 1.0000x reference)
//
#include <hip/hip_runtime.h>
#include <hip/hip_fp16.h>

#define TLEN 16384
#define HD 128

typedef _Float16 half2t __attribute__((ext_vector_type(2)));

__device__ __forceinline__ half2t u2h(unsigned int u) {
    union { unsigned int u; half2t h; } c; c.u = u; return c.h;
}
__device__ __forceinline__ unsigned short f2h_bits(float f) {
    union { _Float16 h; unsigned short s; } c; c.h = (_Float16)f; return c.s;
}
__device__ __forceinline__ half2t mkh2(float a, float b) {
    half2t h; h.x = (_Float16)a; h.y = (_Float16)b; return h;
}
// quad_perm DPP cross-lane (VALU pipe): xor1=[1,0,3,2]=0xB1, xor2=[2,3,0,1]=0x4E
#define DPP_XOR1(x) __int_as_float(__builtin_amdgcn_update_dpp(0, __float_as_int(x), 0xB1, 0xF, 0xF, true))
#define DPP_XOR2(x) __int_as_float(__builtin_amdgcn_update_dpp(0, __float_as_int(x), 0x4E, 0xF, 0xF, true))

// ---------------------------------------------------------------------------
// Sequential GRU scan: 4 independent chains (channel-major — the reference's
// stack().transpose(0,2,1) makes "batch"=channel, "feature"=orig batch row).
// One block per chain, 512 threads = 8 waves, waves_per_eu(2,2).
//
// R9: ONE QUAD PER H-INDEX.  Thread (k=tid>>2, cb=tid&3) owns ALL 6 gate
// rows {k,128+k,256+k} x {Whh,Wih}, cols 32cb..32cb+31, as 96 packed-f16
// registers.  Per step: 4 multicast ds_read_b128 of h, <=96 v_dot2, quad
// all-reduce (2 DPP levels, VALU pipe), full gate computed IN-REGISTER by
// the quad (biases in regs; x-path via per-quad Wc regs), lane0 writes hnew
// to a DOUBLE-BUFFERED h.  => ONE barrier/step, no gg/bias LDS round trip.
// R8 lesson: LDS return-path BW (64B/lane/step) + the 2-barrier gg round
// trip were the bottleneck (~1650 cyc/step); halving lanes + deleting the
// round trip targets ~700 cyc/step.
// ---------------------------------------------------------------------------

#define FORH(X) X(0) X(1) X(2) X(3) X(4) X(5) X(6) X(7) \
                X(8) X(9) X(10) X(11) X(12) X(13) X(14) X(15)

__global__
__attribute__((amdgpu_flat_work_group_size(512, 512), amdgpu_waves_per_eu(2, 2)))
void gru_kernel(
    const float* __restrict__ px,
    const float* __restrict__ py,
    const float* __restrict__ vx,
    const float* __restrict__ vy,
    const float* __restrict__ Wemb,   // [128,4]
    const float* __restrict__ bemb,   // [128]
    const float* __restrict__ Wih,    // [384,128]
    const float* __restrict__ Whh,    // [384,128]
    const float* __restrict__ bih,    // [384]
    const float* __restrict__ bhh,    // [384]
    const int*   __restrict__ step_mask, // [16384]
    const int*   __restrict__ ctxp,      // [1]
    unsigned short* __restrict__ hs)     // [4*16384*128] f16-bits staging
{
    const int bb  = blockIdx.x;   // chain == channel
    const float* xsrc = (bb == 0) ? px : (bb == 1) ? py : (bb == 2) ? vx : vy;
    const int tid = threadIdx.x;
    const int k   = tid >> 2;     // h-index 0..127 (one quad each)
    const int cb  = tid & 3;      // col-block (32 cols)

    __shared__ alignas(16) _Float16 hbuf2[2][HD];       // double-buffered h
    __shared__ alignas(16) unsigned short hring[32][HD]; // 32-slot f16 history
    __shared__ float xbuf[256 * 4];
    __shared__ int   uxbuf[256];
    __shared__ float WembL[HD * 4];
    __shared__ float bembL[HD];

    // ---- weights: 6 rows x 16 packed-f16 = 96 named registers ----
#define DECLROW(r) half2t w##r##_0, w##r##_1, w##r##_2,  w##r##_3, \
                          w##r##_4, w##r##_5, w##r##_6,  w##r##_7, \
                          w##r##_8, w##r##_9, w##r##_10, w##r##_11, \
                          w##r##_12, w##r##_13, w##r##_14, w##r##_15;
    DECLROW(0) DECLROW(1) DECLROW(2) DECLROW(3) DECLROW(4) DECLROW(5)
#undef DECLROW
#define LOADROW(r, PTR) { const float* rp = (PTR) + (cb << 5); \
        const float4 f0 = *(const float4*)(rp+ 0), f1 = *(const float4*)(rp+ 4); \
        const float4 f2 = *(const float4*)(rp+ 8), f3 = *(const float4*)(rp+12); \
        const float4 f4 = *(const float4*)(rp+16), f5 = *(const float4*)(rp+20); \
        const float4 f6 = *(const float4*)(rp+24), f7 = *(const float4*)(rp+28); \
        w##r##_0  = mkh2(f0.x,f0.y); w##r##_1  = mkh2(f0.z,f0.w); \
        w##r##_2  = mkh2(f1.x,f1.y); w##r##_3  = mkh2(f1.z,f1.w); \
        w##r##_4  = mkh2(f2.x,f2.y); w##r##_5  = mkh2(f2.z,f2.w); \
        w##r##_6  = mkh2(f3.x,f3.y); w##r##_7  = mkh2(f3.z,f3.w); \
        w##r##_8  = mkh2(f4.x,f4.y); w##r##_9  = mkh2(f4.z,f4.w); \
        w##r##_10 = mkh2(f5.x,f5.y); w##r##_11 = mkh2(f5.z,f5.w); \
        w##r##_12 = mkh2(f6.x,f6.y); w##r##_13 = mkh2(f6.z,f6.w); \
        w##r##_14 = mkh2(f7.x,f7.y); w##r##_15 = mkh2(f7.z,f7.w); }
    LOADROW(0, Whh + (size_t)(      k) * 128)
    LOADROW(1, Whh + (size_t)(128 + k) * 128)
    LOADROW(2, Whh + (size_t)(256 + k) * 128)
    LOADROW(3, Wih + (size_t)(      k) * 128)
    LOADROW(4, Wih + (size_t)(128 + k) * 128)
    LOADROW(5, Wih + (size_t)(256 + k) * 128)
#undef LOADROW

    const float bhhr = bhh[k], bhhz = bhh[128 + k], bhhn = bhh[256 + k];
    const float bihr = bih[k], bihz = bih[128 + k], bihn = bih[256 + k];

    if (tid < 512) WembL[tid] = Wemb[tid];
    if (tid < 128) bembL[tid] = bemb[tid];
    if (tid < 128) hbuf2[0][tid] = (_Float16)0.f;
    __syncthreads();

    // ---- per-quad embed fold (redundant across the 4 lanes; init-only):
    // Wc[row] (4-wide) and bc[row] = Wc·bemb + bih[row], rows {k,128+k,256+k}
    float4 wcr = {0,0,0,0}, wcz = {0,0,0,0}, wcn = {0,0,0,0};
    float bcr = bihr, bcz = bihz, bcn = bihn;
    {
        const float* r0 = Wih + (size_t)(      k) * 128;
        const float* r1 = Wih + (size_t)(128 + k) * 128;
        const float* r2 = Wih + (size_t)(256 + k) * 128;
        for (int j = 0; j < 128; ++j) {
            const float4 e = *(const float4*)&WembL[j * 4];
            const float eb = bembL[j];
            const float a = r0[j], b = r1[j], c = r2[j];
            wcr.x = fmaf(a, e.x, wcr.x); wcr.y = fmaf(a, e.y, wcr.y);
            wcr.z = fmaf(a, e.z, wcr.z); wcr.w = fmaf(a, e.w, wcr.w);
            bcr   = fmaf(a, eb,  bcr);
            wcz.x = fmaf(b, e.x, wcz.x); wcz.y = fmaf(b, e.y, wcz.y);
            wcz.z = fmaf(b, e.z, wcz.z); wcz.w = fmaf(b, e.w, wcz.w);
            bcz   = fmaf(b, eb,  bcz);
            wcn.x = fmaf(c, e.x, wcn.x); wcn.y = fmaf(c, e.y, wcn.y);
            wcn.z = fmaf(c, e.z, wcn.z); wcn.w = fmaf(c, e.w, wcn.w);
            bcn   = fmaf(c, eb,  bcn);
        }
    }
    const int ctxm = (ctxp[0] < 1) ? 1 : ctxp[0];
    float hold = 0.f;   // this quad's h[k], kept redundantly in all 4 lanes

#define DOT(r, acc) { float a = 0.f; \
        a = __builtin_amdgcn_fdot2(w##r##_0,  hp0,  a, false); \
        a = __builtin_amdgcn_fdot2(w##r##_1,  hp1,  a, false); \
        a = __builtin_amdgcn_fdot2(w##r##_2,  hp2,  a, false); \
        a = __builtin_amdgcn_fdot2(w##r##_3,  hp3,  a, false); \
        a = __builtin_amdgcn_fdot2(w##r##_4,  hp4,  a, false); \
        a = __builtin_amdgcn_fdot2(w##r##_5,  hp5,  a, false); \
        a = __builtin_amdgcn_fdot2(w##r##_6,  hp6,  a, false); \
        a = __builtin_amdgcn_fdot2(w##r##_7,  hp7,  a, false); \
        a = __builtin_amdgcn_fdot2(w##r##_8,  hp8,  a, false); \
        a = __builtin_amdgcn_fdot2(w##r##_9,  hp9,  a, false); \
        a = __builtin_amdgcn_fdot2(w##r##_10, hp10, a, false); \
        a = __builtin_amdgcn_fdot2(w##r##_11, hp11, a, false); \
        a = __builtin_amdgcn_fdot2(w##r##_12, hp12, a, false); \
        a = __builtin_amdgcn_fdot2(w##r##_13, hp13, a, false); \
        a = __builtin_amdgcn_fdot2(w##r##_14, hp14, a, false); \
        a = __builtin_amdgcn_fdot2(w##r##_15, hp15, a, false); \
        acc = a; }
#define QRED(acc) { const float t_ = acc + DPP_XOR1(acc); acc = t_ + DPP_XOR2(t_); }

    for (int t0 = 0; t0 < TLEN; t0 += 256) {
        if (tid < 256) {
            const int gt = t0 + tid;
            xbuf[tid*4+0] = xsrc[0*TLEN + gt];
            xbuf[tid*4+1] = xsrc[1*TLEN + gt];
            xbuf[tid*4+2] = xsrc[2*TLEN + gt];
            xbuf[tid*4+3] = xsrc[3*TLEN + gt];
            uxbuf[tid] = ((gt < ctxm) || (step_mask[gt] == 0)) ? 1 : 0;
        }
        __syncthreads();
        for (int tt = 0; tt < 256; ++tt) {
            const int gt = t0 + tt;
            // ---- flush previous 16-step group (ring half disjoint from
            // current writes); issued at step TOP so the store drain overlaps
            // a full step of compute before the next barrier.
            if ((gt & 15) == 1 && gt > 16 && tid >= 256) {
                const int u  = tid - 256;
                const int G  = (gt >> 4) - 1;       // completed group
                const int sl = u >> 4, g = u & 15;
                const int slot  = ((G & 1) << 4) + sl;
                const int gstep = (G << 4) + sl;
                *(uint4*)&hs[((size_t)(bb * TLEN + gstep) << 7) + (g << 3)] =
                    *(const uint4*)&hring[slot][g << 3];
            }
            const int ux = __builtin_amdgcn_readfirstlane(uxbuf[tt]);
            const uint4* hq = (const uint4*)hbuf2[gt & 1];
            const uint4 q0 = hq[(cb << 2) + 0];
            const uint4 q1 = hq[(cb << 2) + 1];
            const uint4 q2 = hq[(cb << 2) + 2];
            const uint4 q3 = hq[(cb << 2) + 3];
            const half2t hp0  = u2h(q0.x), hp1  = u2h(q0.y),
                         hp2  = u2h(q0.z), hp3  = u2h(q0.w),
                         hp4  = u2h(q1.x), hp5  = u2h(q1.y),
                         hp6  = u2h(q1.z), hp7  = u2h(q1.w),
                         hp8  = u2h(q2.x), hp9  = u2h(q2.y),
                         hp10 = u2h(q2.z), hp11 = u2h(q2.w),
                         hp12 = u2h(q3.x), hp13 = u2h(q3.y),
                         hp14 = u2h(q3.z), hp15 = u2h(q3.w);
            float ghr_, ghz_, ghn_;
            DOT(0, ghr_) DOT(1, ghz_) DOT(2, ghn_)
            QRED(ghr_) QRED(ghz_) QRED(ghn_)
            float gir, giz, gin;
            if (!ux) {
                DOT(3, gir) DOT(4, giz) DOT(5, gin)
                QRED(gir) QRED(giz) QRED(gin)
                gir += bihr; giz += bihz; gin += bihn;
            } else {
                const float4 xv = *(const float4*)&xbuf[tt * 4];
                gir = bcr; giz = bcz; gin = bcn;
                gir = fmaf(wcr.x, xv.x, gir); gir = fmaf(wcr.y, xv.y, gir);
                gir = fmaf(wcr.z, xv.z, gir); gir = fmaf(wcr.w, xv.w, gir);
                giz = fmaf(wcz.x, xv.x, giz); giz = fmaf(wcz.y, xv.y, giz);
                giz = fmaf(wcz.z, xv.z, giz); giz = fmaf(wcz.w, xv.w, giz);
                gin = fmaf(wcn.x, xv.x, gin); gin = fmaf(wcn.y, xv.y, gin);
                gin = fmaf(wcn.z, xv.z, gin); gin = fmaf(wcn.w, xv.w, gin);
            }
            // gates (PyTorch GRUCell: r,z,n), computed by all 4 lanes
            const float r    = 1.f / (1.f + __expf(-(gir + ghr_ + bhhr)));
            const float z    = 1.f / (1.f + __expf(-(giz + ghz_ + bhhz)));
            const float npre = fmaf(r, ghn_ + bhhn, gin);
            const float e2   = __expf(2.f * npre);
            const float n    = 1.f - 2.f / (e2 + 1.f);   // tanh(npre)
            const float hnew = fmaf(z, hold - n, n);     // (1-z)n + z h
            hold = hnew;
            if (cb == 0) hbuf2[(gt + 1) & 1][k] = (_Float16)hnew;
            if (cb == 1) hring[gt & 31][k] = f2h_bits(hnew);
            __syncthreads();
        }
    }
    // final flush: group 1023 (steps 16368..16383, slots 16..31)
    if (tid >= 256) {
        const int u  = tid - 256;
        const int sl = u >> 4, g = u & 15;
        const int slot  = 16 + sl;
        const int gstep = 16368 + sl;
        *(uint4*)&hs[((size_t)(bb * TLEN + gstep) << 7) + (g << 3)] =
            *(const uint4*)&hring[slot][g << 3];
    }
#undef DOT
#undef QRED
}

// ---------------------------------------------------------------------------
// Head MLP over all 65536 hidden states: thread-per-row, weights uniform in
// LDS (broadcast reads), h in registers, y1 in padded LDS (stride 65).
// ---------------------------------------------------------------------------
__global__ __launch_bounds__(64) void head_kernel(
    const float*  __restrict__ W1,  // [64,128]
    const float*  __restrict__ b1,  // [64]
    const float*  __restrict__ W2,  // [64,64]
    const float*  __restrict__ b2,  // [64]
    const float*  __restrict__ W3,  // [2,64]
    const float*  __restrict__ b3,  // [2]
    const __half* __restrict__ hs,
    float*        __restrict__ out)
{
    __shared__ float W1L[64 * 128];
    __shared__ float W2L[64 * 64];
    __shared__ float W3L[2 * 64];
    __shared__ float b1L[64], b2L[64], b3L[2];
    __shared__ float y1L[64 * 65];   // per-thread row, stride 65 (bank pad)

    const int tid = threadIdx.x;
    {
        float4* dst1 = (float4*)W1L; const float4* src1 = (const float4*)W1;
        for (int i = tid; i < 2048; i += 64) dst1[i] = src1[i];
        float4* dst2 = (float4*)W2L; const float4* src2 = (const float4*)W2;
        for (int i = tid; i < 1024; i += 64) dst2[i] = src2[i];
        if (tid < 32) ((float4*)W3L)[tid] = ((const float4*)W3)[tid];
        b1L[tid] = b1[tid];
        b2L[tid] = b2[tid];
        if (tid < 2) b3L[tid] = b3[tid];
    }
    __syncthreads();

    const int row = blockIdx.x * 64 + tid;   // row = bb*16384 + t
    float h[128];
    {
        const uint4* hp = (const uint4*)(hs + (size_t)row * HD);
        #pragma unroll
        for (int c = 0; c < 16; ++c) {
            uint4 q = hp[c];
            const __half2* hh = (const __half2*)&q;
            #pragma unroll
            for (int d = 0; d < 4; ++d) {
                const float2 f = __half22float2(hh[d]);
                h[c*8 + d*2 + 0] = f.x;
                h[c*8 + d*2 + 1] = f.y;
            }
        }
    }
    // layer 1: y1 = elu(W1 h + b1)
    for (int l = 0; l < 64; ++l) {
        float a0 = b1L[l], a1 = 0.f;
        #pragma unroll
        for (int j = 0; j < 128; j += 4) {
            const float4 w = *(const float4*)&W1L[l*128 + j];
            a0 = fmaf(w.x, h[j+0], a0);
            a1 = fmaf(w.y, h[j+1], a1);
            a0 = fmaf(w.z, h[j+2], a0);
            a1 = fmaf(w.w, h[j+3], a1);
        }
        const float acc = a0 + a1;
        y1L[tid * 65 + l] = (acc > 0.f) ? acc : (__expf(acc) - 1.f);
    }
    // layer 2 + layer 3 fused: y3 += W3 * elu(W2 y1 + b2)
    float y30 = b3L[0], y31 = b3L[1];
    for (int l = 0; l < 64; ++l) {
        float a0 = b2L[l], a1 = 0.f;
        const int yb = tid * 65;
        #pragma unroll
        for (int j = 0; j < 64; j += 4) {
            const float4 w = *(const float4*)&W2L[l*64 + j];
            a0 = fmaf(w.x, y1L[yb + j+0], a0);
            a1 = fmaf(w.y, y1L[yb + j+1], a1);
            a0 = fmaf(w.z, y1L[yb + j+2], a0);
            a1 = fmaf(w.w, y1L[yb + j+3], a1);
        }
        const float acc = a0 + a1;
        const float v = (acc > 0.f) ? acc : (__expf(acc) - 1.f);
        y30 = fmaf(W3L[l],      v, y30);
        y31 = fmaf(W3L[64 + l], v, y31);
    }
    out[row]            = y30;
    out[4 * TLEN + row] = y31;
}

extern "C" void kernel_launch(void* const* d_in, const int* in_sizes, int n_in,
                              void* d_out, int out_size, void* d_ws, size_t ws_size,
                              hipStream_t stream) {
    const float* px   = (const float*)d_in[0];
    const float* py   = (const float*)d_in[1];
    const float* vx   = (const float*)d_in[2];
    const float* vy   = (const float*)d_in[3];
    const float* Wemb = (const float*)d_in[4];
    const float* bemb = (const float*)d_in[5];
    const float* Wih  = (const float*)d_in[6];
    const float* Whh  = (const float*)d_in[7];
    const float* bih  = (const float*)d_in[8];
    const float* bhh  = (const float*)d_in[9];
    const float* W1   = (const float*)d_in[10];
    const float* b1   = (const float*)d_in[11];
    const float* W2   = (const float*)d_in[12];
    const float* b2   = (const float*)d_in[13];
    const float* W3   = (const float*)d_in[14];
    const float* b3   = (const float*)d_in[15];
    const int* step_mask = (const int*)d_in[16];
    const int* ctx       = (const int*)d_in[17];
    unsigned short* hs = (unsigned short*)d_ws;  // 4*16384*128 f16-bits = 16.8 MB
    float* out = (float*)d_out;                  // f32, [2][4][16384] flat

    hipLaunchKernelGGL(gru_kernel, dim3(4), dim3(512), 0, stream,
                       px, py, vx, vy, Wemb, bemb, Wih, Whh, bih, bhh,
                       step_mask, ctx, hs);
    hipLaunchKernelGGL(head_kernel, dim3(1024), dim3(64), 0, stream,
                       W1, b1, W2, b2, W3, b3, (const __half*)hs, out);
}